// Round 6
// baseline (226.300 us; speedup 1.0000x reference)
//
#include <hip/hip_runtime.h>
#include <hip/hip_bf16.h>
#include <math.h>

#define L_SEQ 8192
#define B_BATCH 8
#define D_DIM 256
#define BL (B_BATCH * L_SEQ)
#define EPS_F 1.1920929e-07f

typedef __attribute__((ext_vector_type(8))) short short8;
typedef __attribute__((ext_vector_type(4))) float f32x4;
typedef __attribute__((ext_vector_type(4))) unsigned short u16x4;

// ws layout (bytes):
//   [0,       262144)  starts int32 BL (k_scan+)
//   [262144,  524288)  Bpack bf16: 2 segs (M1,M2) x 8 k8 x 16 ct fragments x 64 lanes x 8
//   [524288,  589824)  hard  uint8  BL
//   [589824,  589856)  n_b   int32  8
//   [589856,  589888)  len   int32  8

__device__ inline unsigned short f2bf(float x) {
    __hip_bfloat16 b = __float2bfloat16(x);
    return *(unsigned short*)&b;
}
__device__ inline float bf2f(unsigned short u) {
    __hip_bfloat16 b = *(__hip_bfloat16*)&u;
    return __bfloat162float(b);
}

// ------------------- K1: fused M = Wq^T*Wk - I  ->  bf16 hi/lo MFMA B-fragment pack
__global__ __launch_bounds__(256) void k_matMpack(
    const float* __restrict__ Wq, const float* __restrict__ Wk,
    unsigned short* __restrict__ Bpack) {
    __shared__ float Aq[64][33];
    __shared__ float Ak[64][17];
    const int f   = blockIdx.x;       // 0..127
    const int k8  = f >> 4, ct = f & 15;
    const int tid = threadIdx.x;
    const int n   = tid & 15;         // col within ct tile
    const int k   = tid >> 4;         // 0..15; thread owns rows k and k+16 of the strip
    float a0 = 0.f, a1 = 0.f;
    for (int e0 = 0; e0 < 256; e0 += 64) {
        for (int i = tid; i < 64 * 32; i += 256) {
            const int e = i >> 5, d = i & 31;
            Aq[e][d] = Wq[(e0 + e) * 256 + k8 * 32 + d];
        }
        for (int i = tid; i < 64 * 16; i += 256) {
            const int e = i >> 4, d = i & 15;
            Ak[e][d] = Wk[(e0 + e) * 256 + ct * 16 + d];
        }
        __syncthreads();
#pragma unroll 8
        for (int e = 0; e < 64; ++e) {
            a0 += Aq[e][k] * Ak[e][n];
            a1 += Aq[e][k + 16] * Ak[e][n];
        }
        __syncthreads();
    }
    const int col = ct * 16 + n;
    const float M0 = a0 - ((k8 * 32 + k)      == col ? 1.0f : 0.0f);
    const float M1 = a1 - ((k8 * 32 + k + 16) == col ? 1.0f : 0.0f);
    const unsigned short h0 = f2bf(M0), h1 = f2bf(M1);
    const unsigned short l0 = f2bf(M0 - bf2f(h0)), l1 = f2bf(M1 - bf2f(h1));
    unsigned short* dstH = Bpack + (size_t)(k8 * 16 + ct) * 512;
    unsigned short* dstL = dstH + 128 * 512;
    const int q0 = k >> 3, j0 = k & 7;
    const int q1 = (k + 16) >> 3;
    dstH[(q0 * 16 + n) * 8 + j0] = h0;
    dstH[(q1 * 16 + n) * 8 + j0] = h1;
    dstL[(q0 * 16 + n) * 8 + j0] = l0;
    dstL[(q1 * 16 + n) * 8 + j0] = l1;
}

// ------------------------------ K2: normalize + MFMA correction GEMM + cos + hard bit
// v6: 512 thr = 8 waves, K-SPLIT x col-split: wave (wk, wc) owns ALL 64 rows x
// cols [wc*64,+64) x K-half [wk*128,+128) (8 of 16 strips). vs v5's row-split this
// halves B L2 traffic back to 256 MB (v5: two row-waves double-loaded B -> 512 MB
// ~ 17 TB/s ~ 50% of L2 aggregate -> queueing ate the prefetch distance).
// Partial-K accs merge in the Vpart[8][64] cross-wave reduce (was already there).
// amdgpu_waves_per_eu(4,4): pin exactly 4 waves/SIMD (LDS caps there anyway) ->
// VGPR budget 128, stops the allocator's 64-VGPR squeeze that spilled 8 MB in v5.
#define RS 264   // LDS row stride in bf16 elems: 528 B
#define MM(A,Bv,C) __builtin_amdgcn_mfma_f32_16x16x32_bf16((A),(Bv),(C),0,0,0)
#define MFMA16(V0,V1,V2,V3,BN) \
    acc[0][0]=MM(V0,BN##_0,acc[0][0]); acc[0][1]=MM(V0,BN##_1,acc[0][1]); \
    acc[0][2]=MM(V0,BN##_2,acc[0][2]); acc[0][3]=MM(V0,BN##_3,acc[0][3]); \
    acc[1][0]=MM(V1,BN##_0,acc[1][0]); acc[1][1]=MM(V1,BN##_1,acc[1][1]); \
    acc[1][2]=MM(V1,BN##_2,acc[1][2]); acc[1][3]=MM(V1,BN##_3,acc[1][3]); \
    acc[2][0]=MM(V2,BN##_0,acc[2][0]); acc[2][1]=MM(V2,BN##_1,acc[2][1]); \
    acc[2][2]=MM(V2,BN##_2,acc[2][2]); acc[2][3]=MM(V2,BN##_3,acc[2][3]); \
    acc[3][0]=MM(V3,BN##_0,acc[3][0]); acc[3][1]=MM(V3,BN##_1,acc[3][1]); \
    acc[3][2]=MM(V3,BN##_2,acc[3][2]); acc[3][3]=MM(V3,BN##_3,acc[3][3]);
// B frag offset from Bw for phase J (J<4: seg0 strip wk*4+J; J>=4: seg1 strip 8+wk*4+J-4)
#define LOADB(BN,J) { \
    BN##_0 = Bw[(((J) < 4 ? (J) : (J) + 4) * 16 + 0) * 64]; \
    BN##_1 = Bw[(((J) < 4 ? (J) : (J) + 4) * 16 + 1) * 64]; \
    BN##_2 = Bw[(((J) < 4 ? (J) : (J) + 4) * 16 + 2) * 64]; \
    BN##_3 = Bw[(((J) < 4 ? (J) : (J) + 4) * 16 + 3) * 64]; }
#define COMP_HL(J,BN) { \
    const short8 hv0 = *(const short8*)(hbase2 + ( 0*16)*RS + ((J)&3)*32); \
    const short8 hv1 = *(const short8*)(hbase2 + ( 1*16)*RS + ((J)&3)*32); \
    const short8 hv2 = *(const short8*)(hbase2 + ( 2*16)*RS + ((J)&3)*32); \
    const short8 hv3 = *(const short8*)(hbase2 + ( 3*16)*RS + ((J)&3)*32); \
    MFMA16(hv0, hv1, hv2, hv3, BN); \
    const short8 lv0 = *(const short8*)(lbase2 + ( 0*16)*RS + ((J)&3)*32); \
    const short8 lv1 = *(const short8*)(lbase2 + ( 1*16)*RS + ((J)&3)*32); \
    const short8 lv2 = *(const short8*)(lbase2 + ( 2*16)*RS + ((J)&3)*32); \
    const short8 lv3 = *(const short8*)(lbase2 + ( 3*16)*RS + ((J)&3)*32); \
    MFMA16(lv0, lv1, lv2, lv3, BN); }
#define COMP_H(J,BN) { \
    const short8 hv0 = *(const short8*)(hbase2 + ( 0*16)*RS + ((J)&3)*32); \
    const short8 hv1 = *(const short8*)(hbase2 + ( 1*16)*RS + ((J)&3)*32); \
    const short8 hv2 = *(const short8*)(hbase2 + ( 2*16)*RS + ((J)&3)*32); \
    const short8 hv3 = *(const short8*)(hbase2 + ( 3*16)*RS + ((J)&3)*32); \
    MFMA16(hv0, hv1, hv2, hv3, BN); }

__global__ __launch_bounds__(512) __attribute__((amdgpu_waves_per_eu(4, 4)))
void k_cosmfma(
    const float* __restrict__ hidden, const unsigned short* __restrict__ Bpack,
    const float* __restrict__ noise, unsigned char* __restrict__ hard) {
    __shared__ __attribute__((aligned(16))) unsigned short hiA[65 * RS]; // 34,320 B
    __shared__ __attribute__((aligned(16))) unsigned short loA[65 * RS]; // 34,320 B
    __shared__ float Vpart[8][64];                                       //  2,048 B
    __shared__ float dots[64];                                           //    256 B

    const int tid  = threadIdx.x;
    const int lane = tid & 63;
    const int w    = tid >> 6;        // wave 0..7
    const int wk   = w >> 2;          // K half: strips [wk*4, wk*4+4) per segment
    const int wc   = w & 3;           // col quarter: cols [wc*64, wc*64+64)
    const int wc4  = wc * 4;          // ct base
    const int T0   = blockIdx.x * 64;

    // per-wave B base: frag (wk*4)*16 + wc4, lane-linear
    const short8* __restrict__ Bw = (const short8*)Bpack + ((wk * 4) * 16 + wc4) * 64 + lane;

    // double-buffered B pipeline; preload phase 0 (flies during staging)
    short8 bA_0, bA_1, bA_2, bA_3, bB_0, bB_1, bB_2, bB_3;
    LOADB(bA, 0);

    // ---- stage 9 slab rows [w*8, w*8+8] (token T0-1+row), hi/lo bf16 + pair dots ----
    {
        const int r0 = w * 8;
        int tokA = T0 - 1 + r0; if (tokA < 0) tokA = 0;
        float4 vb0 = ((const float4*)hidden)[(size_t)tokA * 64 + lane];          // row r0
        float4 vb1 = ((const float4*)hidden)[(size_t)(T0 + r0) * 64 + lane];     // row r0+1
        float4 hp4 = {0.f, 0.f, 0.f, 0.f};
#pragma unroll 1
        for (int ii = 0; ii <= 8; ++ii) {
            const float4 vcur = vb0;
            vb0 = vb1;
            if (ii + 2 <= 8)   // prefetch row r0+ii+2 = token T0 + r0 + ii + 1
                vb1 = ((const float4*)hidden)[(size_t)(T0 + r0 + ii + 1) * 64 + lane];
            float ss = vcur.x * vcur.x + vcur.y * vcur.y + vcur.z * vcur.z + vcur.w * vcur.w;
#pragma unroll
            for (int sh = 32; sh >= 1; sh >>= 1) ss += __shfl_xor(ss, sh);
            const float inv = 1.0f / fmaxf(sqrtf(ss), 1e-12f);
            float4 h4;
            h4.x = vcur.x * inv; h4.y = vcur.y * inv;
            h4.z = vcur.z * inv; h4.w = vcur.w * inv;
            const unsigned short hx = f2bf(h4.x), hy = f2bf(h4.y),
                                 hz = f2bf(h4.z), hw2 = f2bf(h4.w);
            const u16x4 hv4 = {hx, hy, hz, hw2};
            const u16x4 lv4 = {f2bf(h4.x - bf2f(hx)), f2bf(h4.y - bf2f(hy)),
                               f2bf(h4.z - bf2f(hz)), f2bf(h4.w - bf2f(hw2))};
            const int i = r0 + ii;
            *(u16x4*)&hiA[i * RS + lane * 4] = hv4;
            *(u16x4*)&loA[i * RS + lane * 4] = lv4;
            if (ii > 0) {   // exact fp32 main dot hn_{i-1}.hn_i  -> token T0 + (i-1)
                float pd = h4.x * hp4.x + h4.y * hp4.y + h4.z * hp4.z + h4.w * hp4.w;
#pragma unroll
                for (int sh = 32; sh >= 1; sh >>= 1) pd += __shfl_xor(pd, sh);
                if (lane == 0) dots[i - 1] = pd;
            }
            hp4 = h4;
        }
    }
    __syncthreads();   // waves read other waves' slab rows below

    // A-frag bases: lane holds A[m][q*8+j]; K offset wk*128 folded into the base;
    // per-phase/af offsets are compile-time immediates.
    const int m = lane & 15, q = lane >> 4;
    const unsigned short* __restrict__ hbase2 = &hiA[m * RS + q * 8 + wk * 128];
    const unsigned short* __restrict__ lbase2 = &loA[m * RS + q * 8 + wk * 128];

    f32x4 acc[4][4];
#pragma unroll
    for (int af = 0; af < 4; ++af)
#pragma unroll
        for (int c = 0; c < 4; ++c) { f32x4 z = {0.f, 0.f, 0.f, 0.f}; acc[af][c] = z; }

    // 8 phases: 0-3 seg0 (hi B; A h+l), 4-7 seg1 (lo B; A h only). Double buffer.
    LOADB(bB, 1) COMP_HL(0, bA)
    LOADB(bA, 2) COMP_HL(1, bB)
    LOADB(bB, 3) COMP_HL(2, bA)
    LOADB(bA, 4) COMP_HL(3, bB)
    LOADB(bB, 5) COMP_H (4, bA)
    LOADB(bA, 6) COMP_H (5, bB)
    LOADB(bB, 7) COMP_H (6, bA)
    COMP_H (7, bB)

    // ---- epilogue: per-row partial over this wave's 64 cols & K half, cross-wave reduce.
    // D row = af*16 + q*4 + r (token T0+row), D col = (wc4+c)*16 + m.
#pragma unroll
    for (int af = 0; af < 4; ++af) {
#pragma unroll
        for (int r = 0; r < 4; ++r) {
            const int row = af * 16 + (q << 2) + r;
            const int ib  = (row + 1) * RS + wc4 * 16 + m;
            float pp = acc[af][0][r] * (bf2f(hiA[ib     ]) + bf2f(loA[ib     ]))
                     + acc[af][1][r] * (bf2f(hiA[ib + 16]) + bf2f(loA[ib + 16]))
                     + acc[af][2][r] * (bf2f(hiA[ib + 32]) + bf2f(loA[ib + 32]))
                     + acc[af][3][r] * (bf2f(hiA[ib + 48]) + bf2f(loA[ib + 48]));
            pp += __shfl_xor(pp, 1);
            pp += __shfl_xor(pp, 2);
            pp += __shfl_xor(pp, 4);
            pp += __shfl_xor(pp, 8);
            if (m == 0) Vpart[w][row] = pp;
        }
    }
    __syncthreads();
    if (tid < 64) {
        const int rl = tid;             // token t = T0 + rl
        const float part = Vpart[0][rl] + Vpart[1][rl] + Vpart[2][rl] + Vpart[3][rl]
                         + Vpart[4][rl] + Vpart[5][rl] + Vpart[6][rl] + Vpart[7][rl];
        const int t = T0 + rl;
        const int l = t & (L_SEQ - 1);
        float p;
        if (l == 0) {
            p = 1.0f;
        } else {
            p = (1.0f - (part + dots[rl])) * 0.5f;
            p = fminf(fmaxf(p, 0.0f), 1.0f);
        }
        p = fminf(fmaxf(p, EPS_F), 1.0f - EPS_F);
        float u = noise[t];
        u = fminf(fmaxf(u, EPS_F), 1.0f - EPS_F);
        const float z = ((logf(p) - log1pf(-p)) + logf(u)) - log1pf(-u);
        hard[t] = (z > 0.0f) ? (unsigned char)1 : (unsigned char)0;
    }
}

// ---------------------- K3: per-row length, forced boundary, scan -> starts, n_b, mask
__global__ __launch_bounds__(1024) void k_scan(
    const float* __restrict__ mask, const unsigned char* __restrict__ hard,
    int* __restrict__ starts, int* __restrict__ nb_arr,
    int* __restrict__ len_arr, float* __restrict__ out_short) {
    __shared__ int wsum[16];
    __shared__ int s_len;
    const int b = blockIdx.x, tid = threadIdx.x;
    const int lane = tid & 63, wv = tid >> 6;   // 16 waves
    const int base = b * L_SEQ;

    // row length = sum(mask): 8 floats per thread
    const float4* m4 = (const float4*)(mask + base);
    const float4 va = m4[tid * 2], vb = m4[tid * 2 + 1];
    int cnt = (va.x != 0.f) + (va.y != 0.f) + (va.z != 0.f) + (va.w != 0.f)
            + (vb.x != 0.f) + (vb.y != 0.f) + (vb.z != 0.f) + (vb.w != 0.f);
#pragma unroll
    for (int sh = 32; sh >= 1; sh >>= 1) cnt += __shfl_xor(cnt, sh);
    if (lane == 0) wsum[wv] = cnt;
    __syncthreads();
    if (tid == 0) {
        int s = 0;
        for (int i = 0; i < 16; ++i) s += wsum[i];
        s_len = s;
    }
    __syncthreads();
    const int len = s_len;

    // adjusted hard bits for this thread's 8 tokens [8*tid, 8*tid+8)
    const int i0 = tid * 8;
    const uint2 hb = ((const uint2*)(hard + base))[tid];
    int c = 0;
    unsigned int bits = 0;
#pragma unroll
    for (int j = 0; j < 8; ++j) {
        const unsigned int byte = ((j < 4 ? hb.x : hb.y) >> (8 * (j & 3))) & 0xffu;
        int h = ((i0 + j) < len) ? (int)(byte != 0u) : 0;
        if (len < L_SEQ && (i0 + j) == len - 1) h = 1;  // forced boundary at last real token
        bits |= (unsigned int)h << j;
        c += h;
    }
    // inclusive wave scan of counts
    int x = c;
#pragma unroll
    for (int ofs = 1; ofs < 64; ofs <<= 1) {
        const int t = __shfl_up(x, ofs);
        if (lane >= ofs) x += t;
    }
    if (lane == 63) wsum[wv] = x;
    __syncthreads();
    int woff = 0, nb = 0;
#pragma unroll
    for (int i = 0; i < 16; ++i) {
        const int t = wsum[i];
        nb += t;
        if (i < wv) woff += t;
    }
    int run = woff + x - c;   // exclusive prefix for this thread
#pragma unroll
    for (int j = 0; j < 8; ++j)
        if ((bits >> j) & 1u) { starts[base + run] = i0 + j; ++run; }

    if (tid == 0) { nb_arr[b] = nb; len_arr[b] = len; }

    float4 o0, o1;
    o0.x = (i0 + 0) < nb ? 1.f : 0.f; o0.y = (i0 + 1) < nb ? 1.f : 0.f;
    o0.z = (i0 + 2) < nb ? 1.f : 0.f; o0.w = (i0 + 3) < nb ? 1.f : 0.f;
    o1.x = (i0 + 4) < nb ? 1.f : 0.f; o1.y = (i0 + 5) < nb ? 1.f : 0.f;
    o1.z = (i0 + 6) < nb ? 1.f : 0.f; o1.w = (i0 + 7) < nb ? 1.f : 0.f;
    float4* os4 = (float4*)(out_short + base);
    os4[tid * 2] = o0;
    os4[tid * 2 + 1] = o1;
}

// --------------------------------------------- K4: one wave per segment, mean-pool
__global__ __launch_bounds__(256) void k_pool(
    const float* __restrict__ hidden, const int* __restrict__ starts,
    const int* __restrict__ nb_arr, const int* __restrict__ len_arr,
    float* __restrict__ pooled) {
    const int tid  = threadIdx.x;
    const int lane = tid & 63;
    const int wid  = blockIdx.x * 4 + (tid >> 6);
    const int b    = wid >> 13;       // / 8192
    const int s    = wid & (L_SEQ - 1);
    const int nb   = nb_arr[b];

    float4 res = {0.f, 0.f, 0.f, 0.f};
    if (s < nb) {
        const int start = (s == 0) ? 0 : starts[b * L_SEQ + s];
        const int end   = (s + 1 < nb) ? starts[b * L_SEQ + s + 1] : len_arr[b];
        float4 acc = {0.f, 0.f, 0.f, 0.f};
        for (int t = start; t < end; ++t) {
            const float4 v = ((const float4*)hidden)[(b * L_SEQ + t) * 64 + lane];
            acc.x += v.x; acc.y += v.y; acc.z += v.z; acc.w += v.w;
        }
        const float cntf = (float)(end - start);
        res.x = acc.x / cntf; res.y = acc.y / cntf; res.z = acc.z / cntf; res.w = acc.w / cntf;
    }
    ((float4*)pooled)[(size_t)wid * 64 + lane] = res;
}

// ---------------------------------------------------- K5: scalars (loss via lgamma)
__global__ void k_final(const int* __restrict__ nb_arr, const int* __restrict__ len_arr,
                        float* __restrict__ out_scal) {
    if (threadIdx.x == 0) {
        int nb = 0, ln = 0;
        for (int b = 0; b < B_BATCH; ++b) { nb += nb_arr[b]; ln += len_arr[b]; }
        const double k = (double)nb, n = (double)ln;
        const double logp = lgamma(n + 1.0) - lgamma(k + 1.0) - lgamma(n - k + 1.0)
                            + k * log(0.2) + (n - k) * log(0.8);
        const double loss = -logp / n;
        out_scal[0] = (float)loss;
        out_scal[1] = (float)nb;
        out_scal[2] = (float)ln;
    }
}

extern "C" void kernel_launch(void* const* d_in, const int* in_sizes, int n_in,
                              void* d_out, int out_size, void* d_ws, size_t ws_size,
                              hipStream_t stream) {
    const float* hidden = (const float*)d_in[0];
    const float* Wq     = (const float*)d_in[1];
    const float* Wk     = (const float*)d_in[2];
    const float* noise  = (const float*)d_in[3];
    const float* mask   = (const float*)d_in[4];
    float* out = (float*)d_out;
    char* ws = (char*)d_ws;

    int*            starts = (int*)(ws);
    unsigned short* Bpack  = (unsigned short*)(ws + 262144);
    unsigned char*  hard   = (unsigned char*)(ws + 524288);
    int*            nb_arr = (int*)(ws + 589824);
    int*            len_arr= (int*)(ws + 589856);

    float* pooled = out;
    float* scal   = out + (size_t)BL * D_DIM;
    float* shortm = scal + 3;

    k_matMpack<<<128, 256, 0, stream>>>(Wq, Wk, Bpack);
    k_cosmfma <<<BL / 64, 512, 0, stream>>>(hidden, Bpack, noise, hard);
    k_scan    <<<B_BATCH, 1024, 0, stream>>>(mask, hard, starts, nb_arr, len_arr, shortm);
    k_pool    <<<BL / 4, 256, 0, stream>>>(hidden, starts, nb_arr, len_arr, pooled);
    k_final   <<<1, 64, 0, stream>>>(nb_arr, len_arr, scal);
}

// Round 7
// 184.408 us; speedup vs baseline: 1.2272x; 1.2272x over previous
//
#include <hip/hip_runtime.h>
#include <hip/hip_bf16.h>
#include <math.h>

#define L_SEQ 8192
#define B_BATCH 8
#define D_DIM 256
#define BL (B_BATCH * L_SEQ)
#define EPS_F 1.1920929e-07f

typedef __attribute__((ext_vector_type(8))) short short8;
typedef __attribute__((ext_vector_type(4))) float f32x4;
typedef __attribute__((ext_vector_type(4))) unsigned short u16x4;

// ws layout (bytes):
//   [0,       262144)  starts int32 BL (k_scan+)
//   [262144,  524288)  Bpack bf16: 2 segs (M1,M2) x 8 k8 x 16 ct fragments x 64 lanes x 8
//   [524288,  589824)  hard  uint8  BL
//   [589824,  589856)  n_b   int32  8
//   [589856,  589888)  len   int32  8

__device__ inline unsigned short f2bf(float x) {
    __hip_bfloat16 b = __float2bfloat16(x);
    return *(unsigned short*)&b;
}
__device__ inline float bf2f(unsigned short u) {
    __hip_bfloat16 b = *(__hip_bfloat16*)&u;
    return __bfloat162float(b);
}

// ------------------- K1: fused M = Wq^T*Wk - I  ->  bf16 hi/lo MFMA B-fragment pack
__global__ __launch_bounds__(256) void k_matMpack(
    const float* __restrict__ Wq, const float* __restrict__ Wk,
    unsigned short* __restrict__ Bpack) {
    __shared__ float Aq[64][33];
    __shared__ float Ak[64][17];
    const int f   = blockIdx.x;       // 0..127
    const int k8  = f >> 4, ct = f & 15;
    const int tid = threadIdx.x;
    const int n   = tid & 15;         // col within ct tile
    const int k   = tid >> 4;         // 0..15; thread owns rows k and k+16 of the strip
    float a0 = 0.f, a1 = 0.f;
    for (int e0 = 0; e0 < 256; e0 += 64) {
        for (int i = tid; i < 64 * 32; i += 256) {
            const int e = i >> 5, d = i & 31;
            Aq[e][d] = Wq[(e0 + e) * 256 + k8 * 32 + d];
        }
        for (int i = tid; i < 64 * 16; i += 256) {
            const int e = i >> 4, d = i & 15;
            Ak[e][d] = Wk[(e0 + e) * 256 + ct * 16 + d];
        }
        __syncthreads();
#pragma unroll 8
        for (int e = 0; e < 64; ++e) {
            a0 += Aq[e][k] * Ak[e][n];
            a1 += Aq[e][k + 16] * Ak[e][n];
        }
        __syncthreads();
    }
    const int col = ct * 16 + n;
    const float M0 = a0 - ((k8 * 32 + k)      == col ? 1.0f : 0.0f);
    const float M1 = a1 - ((k8 * 32 + k + 16) == col ? 1.0f : 0.0f);
    const unsigned short h0 = f2bf(M0), h1 = f2bf(M1);
    const unsigned short l0 = f2bf(M0 - bf2f(h0)), l1 = f2bf(M1 - bf2f(h1));
    unsigned short* dstH = Bpack + (size_t)(k8 * 16 + ct) * 512;
    unsigned short* dstL = dstH + 128 * 512;
    const int q0 = k >> 3, j0 = k & 7;
    const int q1 = (k + 16) >> 3;
    dstH[(q0 * 16 + n) * 8 + j0] = h0;
    dstH[(q1 * 16 + n) * 8 + j0] = h1;
    dstL[(q0 * 16 + n) * 8 + j0] = l0;
    dstL[(q1 * 16 + n) * 8 + j0] = l1;
}

// ------------------------------ K2: normalize + MFMA correction GEMM + cos + hard bit
// v7: 256 thr = 4 waves, 32-TOKEN tiles (grid 2048). Why: 512-thr blocks pin arch
// VGPR at 64 on this compiler (v5/v6 spilled: 8 MB / 112 MB scratch); 256-thr blocks
// reliably get ~124 (v3/v4, zero spill). Occupancy instead comes from halving LDS:
// 33-row slab -> ~35.5 KB -> 4 blocks/CU = 4 waves/SIMD (v5's occupancy, v4's regs).
// Col-split: wave w owns all 32 rows x cols [w*64,+64) (each B frag read by one wave).
// B traffic 512 MB L2 aggregate (~v5 level, absorbed fine). 3-buffer B pipeline.
#define RS 264   // LDS row stride in bf16 elems: 528 B
#define MM(A,Bv,C) __builtin_amdgcn_mfma_f32_16x16x32_bf16((A),(Bv),(C),0,0,0)
#define MFMA8(V0,V1,BN) \
    acc[0][0]=MM(V0,BN##_0,acc[0][0]); acc[0][1]=MM(V0,BN##_1,acc[0][1]); \
    acc[0][2]=MM(V0,BN##_2,acc[0][2]); acc[0][3]=MM(V0,BN##_3,acc[0][3]); \
    acc[1][0]=MM(V1,BN##_0,acc[1][0]); acc[1][1]=MM(V1,BN##_1,acc[1][1]); \
    acc[1][2]=MM(V1,BN##_2,acc[1][2]); acc[1][3]=MM(V1,BN##_3,acc[1][3]);
#define LOADB(BN,S) \
    BN##_0 = Bld[(((S) * 16) + wc4 + 0) * 64]; \
    BN##_1 = Bld[(((S) * 16) + wc4 + 1) * 64]; \
    BN##_2 = Bld[(((S) * 16) + wc4 + 2) * 64]; \
    BN##_3 = Bld[(((S) * 16) + wc4 + 3) * 64];
#define STRIP_HL(S,BN) { \
    const int co = ((S) & 7) * 32; \
    const short8 hv0 = *(const short8*)(hA0 + co), hv1 = *(const short8*)(hA1 + co); \
    const short8 lv0 = *(const short8*)(lA0 + co), lv1 = *(const short8*)(lA1 + co); \
    MFMA8(hv0, hv1, BN); \
    MFMA8(lv0, lv1, BN); \
    LOADB(BN, (S) + 3); }
#define STRIP_H(S,BN) { \
    const int co = ((S) & 7) * 32; \
    const short8 hv0 = *(const short8*)(hA0 + co), hv1 = *(const short8*)(hA1 + co); \
    MFMA8(hv0, hv1, BN); \
    if ((S) + 3 < 16) { LOADB(BN, (S) + 3); } }

__global__ __launch_bounds__(256, 2) void k_cosmfma(
    const float* __restrict__ hidden, const unsigned short* __restrict__ Bpack,
    const float* __restrict__ noise, unsigned char* __restrict__ hard) {
    __shared__ __attribute__((aligned(16))) unsigned short hiA[33 * RS]; // 17,424 B
    __shared__ __attribute__((aligned(16))) unsigned short loA[33 * RS]; // 17,424 B
    __shared__ float Vpart[4][32];                                       //    512 B
    __shared__ float dots[32];                                           //    128 B

    const int tid  = threadIdx.x;
    const int lane = tid & 63;
    const int w    = tid >> 6;        // wave 0..3
    const int wc4  = w * 4;           // ct base: cols [w*64, w*64+64)
    const int T0   = blockIdx.x * 32;

    const short8* __restrict__ Bld = (const short8*)Bpack + lane;

    // 3-buffer B pipeline; preload strips 0,1,2 (fly during staging)
    short8 bA_0, bA_1, bA_2, bA_3, bB_0, bB_1, bB_2, bB_3, bC_0, bC_1, bC_2, bC_3;
    LOADB(bA, 0);
    LOADB(bB, 1);
    LOADB(bC, 2);

    // ---- stage 9 slab rows [w*8, w*8+8] (token T0-1+row), hi/lo bf16 + pair dots ----
    {
        const int r0 = w * 8;
        int tokA = T0 - 1 + r0; if (tokA < 0) tokA = 0;
        float4 vb0 = ((const float4*)hidden)[(size_t)tokA * 64 + lane];          // row r0
        float4 vb1 = ((const float4*)hidden)[(size_t)(T0 + r0) * 64 + lane];     // row r0+1
        float4 hp4 = {0.f, 0.f, 0.f, 0.f};
#pragma unroll 1
        for (int ii = 0; ii <= 8; ++ii) {
            const float4 vcur = vb0;
            vb0 = vb1;
            if (ii + 2 <= 8)   // prefetch row r0+ii+2 = token T0 + r0 + ii + 1
                vb1 = ((const float4*)hidden)[(size_t)(T0 + r0 + ii + 1) * 64 + lane];
            float ss = vcur.x * vcur.x + vcur.y * vcur.y + vcur.z * vcur.z + vcur.w * vcur.w;
#pragma unroll
            for (int sh = 32; sh >= 1; sh >>= 1) ss += __shfl_xor(ss, sh);
            const float inv = 1.0f / fmaxf(sqrtf(ss), 1e-12f);
            float4 h4;
            h4.x = vcur.x * inv; h4.y = vcur.y * inv;
            h4.z = vcur.z * inv; h4.w = vcur.w * inv;
            const unsigned short hx = f2bf(h4.x), hy = f2bf(h4.y),
                                 hz = f2bf(h4.z), hw2 = f2bf(h4.w);
            const u16x4 hv4 = {hx, hy, hz, hw2};
            const u16x4 lv4 = {f2bf(h4.x - bf2f(hx)), f2bf(h4.y - bf2f(hy)),
                               f2bf(h4.z - bf2f(hz)), f2bf(h4.w - bf2f(hw2))};
            const int i = r0 + ii;
            *(u16x4*)&hiA[i * RS + lane * 4] = hv4;
            *(u16x4*)&loA[i * RS + lane * 4] = lv4;
            if (ii > 0) {   // exact fp32 main dot hn_{i-1}.hn_i  -> token T0 + (i-1)
                float pd = h4.x * hp4.x + h4.y * hp4.y + h4.z * hp4.z + h4.w * hp4.w;
#pragma unroll
                for (int sh = 32; sh >= 1; sh >>= 1) pd += __shfl_xor(pd, sh);
                if (lane == 0) dots[i - 1] = pd;
            }
            hp4 = h4;
        }
    }
    __syncthreads();   // waves read other waves' slab rows below

    // A-frag pointers: frag af covers slab rows af*16 + m; lane holds A[m][q*8+j]
    const int m = lane & 15, q = lane >> 4;
    const unsigned short* __restrict__ hA0 = &hiA[( 0 + m) * RS + q * 8];
    const unsigned short* __restrict__ hA1 = &hiA[(16 + m) * RS + q * 8];
    const unsigned short* __restrict__ lA0 = &loA[( 0 + m) * RS + q * 8];
    const unsigned short* __restrict__ lA1 = &loA[(16 + m) * RS + q * 8];

    f32x4 acc[2][4];
#pragma unroll
    for (int af = 0; af < 2; ++af)
#pragma unroll
        for (int c = 0; c < 4; ++c) { f32x4 z = {0.f, 0.f, 0.f, 0.f}; acc[af][c] = z; }

    // strips 0..7: seg0 (hi B; A h+l); strips 8..15: seg1 (lo B; A h only)
    STRIP_HL(0, bA)  STRIP_HL(1, bB)  STRIP_HL(2, bC)  STRIP_HL(3, bA)
    STRIP_HL(4, bB)  STRIP_HL(5, bC)  STRIP_HL(6, bA)  STRIP_HL(7, bB)
    STRIP_H (8, bC)  STRIP_H (9, bA)  STRIP_H (10, bB) STRIP_H (11, bC)
    STRIP_H (12, bA) STRIP_H (13, bB) STRIP_H (14, bC) STRIP_H (15, bA)

    // ---- epilogue: per-row partial over this wave's 64 cols, then cross-wave reduce ----
    // D row = af*16 + q*4 + r (token T0+row), D col = (wc4+c)*16 + m.
#pragma unroll
    for (int af = 0; af < 2; ++af) {
#pragma unroll
        for (int r = 0; r < 4; ++r) {
            const int row = af * 16 + (q << 2) + r;
            const int ib  = (row + 1) * RS + wc4 * 16 + m;
            float pp = acc[af][0][r] * (bf2f(hiA[ib     ]) + bf2f(loA[ib     ]))
                     + acc[af][1][r] * (bf2f(hiA[ib + 16]) + bf2f(loA[ib + 16]))
                     + acc[af][2][r] * (bf2f(hiA[ib + 32]) + bf2f(loA[ib + 32]))
                     + acc[af][3][r] * (bf2f(hiA[ib + 48]) + bf2f(loA[ib + 48]));
            pp += __shfl_xor(pp, 1);
            pp += __shfl_xor(pp, 2);
            pp += __shfl_xor(pp, 4);
            pp += __shfl_xor(pp, 8);
            if (m == 0) Vpart[w][row] = pp;
        }
    }
    __syncthreads();
    if (tid < 32) {
        const int rl = tid;             // token t = T0 + rl
        const float part = Vpart[0][rl] + Vpart[1][rl] + Vpart[2][rl] + Vpart[3][rl];
        const int t = T0 + rl;
        const int l = t & (L_SEQ - 1);
        float p;
        if (l == 0) {
            p = 1.0f;
        } else {
            p = (1.0f - (part + dots[rl])) * 0.5f;
            p = fminf(fmaxf(p, 0.0f), 1.0f);
        }
        p = fminf(fmaxf(p, EPS_F), 1.0f - EPS_F);
        float u = noise[t];
        u = fminf(fmaxf(u, EPS_F), 1.0f - EPS_F);
        const float z = ((logf(p) - log1pf(-p)) + logf(u)) - log1pf(-u);
        hard[t] = (z > 0.0f) ? (unsigned char)1 : (unsigned char)0;
    }
}

// ---------------------- K3: per-row length, forced boundary, scan -> starts, n_b, mask
__global__ __launch_bounds__(1024) void k_scan(
    const float* __restrict__ mask, const unsigned char* __restrict__ hard,
    int* __restrict__ starts, int* __restrict__ nb_arr,
    int* __restrict__ len_arr, float* __restrict__ out_short) {
    __shared__ int wsum[16];
    __shared__ int s_len;
    const int b = blockIdx.x, tid = threadIdx.x;
    const int lane = tid & 63, wv = tid >> 6;   // 16 waves
    const int base = b * L_SEQ;

    // row length = sum(mask): 8 floats per thread
    const float4* m4 = (const float4*)(mask + base);
    const float4 va = m4[tid * 2], vb = m4[tid * 2 + 1];
    int cnt = (va.x != 0.f) + (va.y != 0.f) + (va.z != 0.f) + (va.w != 0.f)
            + (vb.x != 0.f) + (vb.y != 0.f) + (vb.z != 0.f) + (vb.w != 0.f);
#pragma unroll
    for (int sh = 32; sh >= 1; sh >>= 1) cnt += __shfl_xor(cnt, sh);
    if (lane == 0) wsum[wv] = cnt;
    __syncthreads();
    if (tid == 0) {
        int s = 0;
        for (int i = 0; i < 16; ++i) s += wsum[i];
        s_len = s;
    }
    __syncthreads();
    const int len = s_len;

    // adjusted hard bits for this thread's 8 tokens [8*tid, 8*tid+8)
    const int i0 = tid * 8;
    const uint2 hb = ((const uint2*)(hard + base))[tid];
    int c = 0;
    unsigned int bits = 0;
#pragma unroll
    for (int j = 0; j < 8; ++j) {
        const unsigned int byte = ((j < 4 ? hb.x : hb.y) >> (8 * (j & 3))) & 0xffu;
        int h = ((i0 + j) < len) ? (int)(byte != 0u) : 0;
        if (len < L_SEQ && (i0 + j) == len - 1) h = 1;  // forced boundary at last real token
        bits |= (unsigned int)h << j;
        c += h;
    }
    // inclusive wave scan of counts
    int x = c;
#pragma unroll
    for (int ofs = 1; ofs < 64; ofs <<= 1) {
        const int t = __shfl_up(x, ofs);
        if (lane >= ofs) x += t;
    }
    if (lane == 63) wsum[wv] = x;
    __syncthreads();
    int woff = 0, nb = 0;
#pragma unroll
    for (int i = 0; i < 16; ++i) {
        const int t = wsum[i];
        nb += t;
        if (i < wv) woff += t;
    }
    int run = woff + x - c;   // exclusive prefix for this thread
#pragma unroll
    for (int j = 0; j < 8; ++j)
        if ((bits >> j) & 1u) { starts[base + run] = i0 + j; ++run; }

    if (tid == 0) { nb_arr[b] = nb; len_arr[b] = len; }

    float4 o0, o1;
    o0.x = (i0 + 0) < nb ? 1.f : 0.f; o0.y = (i0 + 1) < nb ? 1.f : 0.f;
    o0.z = (i0 + 2) < nb ? 1.f : 0.f; o0.w = (i0 + 3) < nb ? 1.f : 0.f;
    o1.x = (i0 + 4) < nb ? 1.f : 0.f; o1.y = (i0 + 5) < nb ? 1.f : 0.f;
    o1.z = (i0 + 6) < nb ? 1.f : 0.f; o1.w = (i0 + 7) < nb ? 1.f : 0.f;
    float4* os4 = (float4*)(out_short + base);
    os4[tid * 2] = o0;
    os4[tid * 2 + 1] = o1;
}

// --------------------------------------------- K4: one wave per segment, mean-pool
__global__ __launch_bounds__(256) void k_pool(
    const float* __restrict__ hidden, const int* __restrict__ starts,
    const int* __restrict__ nb_arr, const int* __restrict__ len_arr,
    float* __restrict__ pooled) {
    const int tid  = threadIdx.x;
    const int lane = tid & 63;
    const int wid  = blockIdx.x * 4 + (tid >> 6);
    const int b    = wid >> 13;       // / 8192
    const int s    = wid & (L_SEQ - 1);
    const int nb   = nb_arr[b];

    float4 res = {0.f, 0.f, 0.f, 0.f};
    if (s < nb) {
        const int start = (s == 0) ? 0 : starts[b * L_SEQ + s];
        const int end   = (s + 1 < nb) ? starts[b * L_SEQ + s + 1] : len_arr[b];
        float4 acc = {0.f, 0.f, 0.f, 0.f};
        for (int t = start; t < end; ++t) {
            const float4 v = ((const float4*)hidden)[(b * L_SEQ + t) * 64 + lane];
            acc.x += v.x; acc.y += v.y; acc.z += v.z; acc.w += v.w;
        }
        const float cntf = (float)(end - start);
        res.x = acc.x / cntf; res.y = acc.y / cntf; res.z = acc.z / cntf; res.w = acc.w / cntf;
    }
    ((float4*)pooled)[(size_t)wid * 64 + lane] = res;
}

// ---------------------------------------------------- K5: scalars (loss via lgamma)
__global__ void k_final(const int* __restrict__ nb_arr, const int* __restrict__ len_arr,
                        float* __restrict__ out_scal) {
    if (threadIdx.x == 0) {
        int nb = 0, ln = 0;
        for (int b = 0; b < B_BATCH; ++b) { nb += nb_arr[b]; ln += len_arr[b]; }
        const double k = (double)nb, n = (double)ln;
        const double logp = lgamma(n + 1.0) - lgamma(k + 1.0) - lgamma(n - k + 1.0)
                            + k * log(0.2) + (n - k) * log(0.8);
        const double loss = -logp / n;
        out_scal[0] = (float)loss;
        out_scal[1] = (float)nb;
        out_scal[2] = (float)ln;
    }
}

extern "C" void kernel_launch(void* const* d_in, const int* in_sizes, int n_in,
                              void* d_out, int out_size, void* d_ws, size_t ws_size,
                              hipStream_t stream) {
    const float* hidden = (const float*)d_in[0];
    const float* Wq     = (const float*)d_in[1];
    const float* Wk     = (const float*)d_in[2];
    const float* noise  = (const float*)d_in[3];
    const float* mask   = (const float*)d_in[4];
    float* out = (float*)d_out;
    char* ws = (char*)d_ws;

    int*            starts = (int*)(ws);
    unsigned short* Bpack  = (unsigned short*)(ws + 262144);
    unsigned char*  hard   = (unsigned char*)(ws + 524288);
    int*            nb_arr = (int*)(ws + 589824);
    int*            len_arr= (int*)(ws + 589856);

    float* pooled = out;
    float* scal   = out + (size_t)BL * D_DIM;
    float* shortm = scal + 3;

    k_matMpack<<<128, 256, 0, stream>>>(Wq, Wk, Bpack);
    k_cosmfma <<<BL / 32, 256, 0, stream>>>(hidden, Bpack, noise, hard);
    k_scan    <<<B_BATCH, 1024, 0, stream>>>(mask, hard, starts, nb_arr, len_arr, shortm);
    k_pool    <<<BL / 4, 256, 0, stream>>>(hidden, starts, nb_arr, len_arr, pooled);
    k_final   <<<1, 64, 0, stream>>>(nb_arr, len_arr, scal);
}